// Round 1
// baseline (1537.008 us; speedup 1.0000x reference)
//
#include <hip/hip_runtime.h>
#include <hip/hip_bf16.h>
#include <stdint.h>
#include <stddef.h>

// JAX RNG scheme: 1 = threefry_partitionable (modern default), 0 = original iota-halves
#ifndef PARTITIONABLE
#define PARTITIONABLE 1
#endif

// ---------------- threefry2x32 (exact JAX) ----------------
__host__ __device__ __forceinline__ uint32_t rotl32(uint32_t x, int d){ return (x<<d)|(x>>(32-d)); }

__host__ __device__ __forceinline__ void tf4(uint32_t&x0, uint32_t&x1, int r0,int r1,int r2,int r3){
  x0+=x1; x1=rotl32(x1,r0); x1^=x0;
  x0+=x1; x1=rotl32(x1,r1); x1^=x0;
  x0+=x1; x1=rotl32(x1,r2); x1^=x0;
  x0+=x1; x1=rotl32(x1,r3); x1^=x0;
}
__host__ __device__ __forceinline__ void threefry2x32(uint32_t k0,uint32_t k1,uint32_t x0,uint32_t x1,
                                                      uint32_t&y0,uint32_t&y1){
  uint32_t ks2 = k0^k1^0x1BD11BDAu;
  x0+=k0; x1+=k1;
  tf4(x0,x1,13,15,26,6);  x0+=k1;  x1+=ks2+1u;
  tf4(x0,x1,17,29,16,24); x0+=ks2; x1+=k0+2u;
  tf4(x0,x1,13,15,26,6);  x0+=k0;  x1+=k1+3u;
  tf4(x0,x1,17,29,16,24); x0+=k1;  x1+=ks2+4u;
  tf4(x0,x1,13,15,26,6);  x0+=ks2; x1+=k0+5u;
  y0=x0; y1=x1;
}

__device__ __forceinline__ uint32_t random_bits32(uint32_t k0,uint32_t k1,uint32_t idx, uint32_t half){
#if PARTITIONABLE
  uint32_t y0,y1; threefry2x32(k0,k1, 0u, idx, y0,y1);
  (void)half;
  return y0 ^ y1;
#else
  uint32_t y0,y1;
  if (idx < half) { threefry2x32(k0,k1, idx, idx+half, y0,y1); return y0; }
  else            { threefry2x32(k0,k1, idx-half, idx, y0,y1); return y1; }
#endif
}

// ---------------- generic f32 GEMM: C = A@B (+bias), K%16==0, M%BM==0, N%BN==0 ----------------
template<int BM, int BN, int TM, int TN>
__global__ __launch_bounds__(256) void gemm_f32(
    const float* __restrict__ A, const float* __restrict__ B,
    const float* __restrict__ bias, float* __restrict__ C,
    int M, int N, int K){
  constexpr int BK = 16;
  constexpr int PAD = 4;                      // break bank aliasing on As writes
  __shared__ float As[BK][BM+PAD];
  __shared__ float Bs[BK][BN];
  const int tid = threadIdx.x;
  const int bm = blockIdx.y*BM, bn = blockIdx.x*BN;
  constexpr int NT = BN/TN;
  const int tc = tid % NT, tr = tid / NT;
  float acc[TM][TN];
  #pragma unroll
  for (int i=0;i<TM;i++)
    #pragma unroll
    for(int j=0;j<TN;j++) acc[i][j]=0.f;

  constexpr int AQ = BM*(BK/4);
  constexpr int BQ = BK*(BN/4);

  for (int k0=0;k0<K;k0+=BK){
    #pragma unroll
    for (int q=tid; q<AQ; q+=256){
      int m = q >> 2, kq = q & 3;             // BK/4 == 4
      const float4 v = *(const float4*)&A[(size_t)(bm+m)*K + k0 + kq*4];
      As[kq*4+0][m]=v.x; As[kq*4+1][m]=v.y; As[kq*4+2][m]=v.z; As[kq*4+3][m]=v.w;
    }
    #pragma unroll
    for (int q=tid; q<BQ; q+=256){
      int kk = q / (BN/4), nq = q % (BN/4);
      *(float4*)&Bs[kk][nq*4] = *(const float4*)&B[(size_t)(k0+kk)*N + bn + nq*4];
    }
    __syncthreads();
    #pragma unroll
    for (int kk=0;kk<BK;kk++){
      float a[TM], b[TN];
      #pragma unroll
      for (int i=0;i<TM;i++) a[i]=As[kk][tr*TM+i];
      #pragma unroll
      for (int j=0;j<TN;j++) b[j]=Bs[kk][tc*TN+j];
      #pragma unroll
      for (int i=0;i<TM;i++)
        #pragma unroll
        for (int j=0;j<TN;j++)
          acc[i][j] += a[i]*b[j];
    }
    __syncthreads();
  }
  #pragma unroll
  for (int i=0;i<TM;i++){
    const size_t row = (size_t)(bm + tr*TM + i);
    #pragma unroll
    for (int j=0;j<TN;j++){
      const size_t col = (size_t)(bn + tc*TN + j);
      float v = acc[i][j];
      if (bias) v += bias[col];
      C[row*(size_t)N + col] = v;
    }
  }
}

// ---------------- codebook first layer: X0 = bits(0..255)@w0 + b0, [256,1024] ----------------
__global__ __launch_bounds__(256) void cb_fc0_kernel(const float* __restrict__ w0,
                                                     const float* __restrict__ b0,
                                                     float* __restrict__ X0){
  int g = blockIdx.x*256 + threadIdx.x;       // 262144 total
  int i = g >> 10, c = g & 1023;
  float acc = b0[c];
  #pragma unroll
  for (int j=0;j<8;j++) if ((i >> (7-j)) & 1) acc += w0[j*1024 + c];
  X0[g] = acc;
}

// ---------------- BN (batch stats over 256 rows) + ReLU; X,Y: [256, C] ----------------
__global__ __launch_bounds__(256) void bn_relu_kernel(const float* __restrict__ X,
                                                      const float* __restrict__ gma,
                                                      const float* __restrict__ bta,
                                                      float* __restrict__ Y, int C){
  const int c0 = blockIdx.x*64;
  const int t = threadIdx.x;
  const int cl = t & 63, rl = t >> 6;         // 4 row-lanes x 64 cols
  const int c = c0 + cl;
  __shared__ float red[4][64];
  __shared__ float mcol[64], vcol[64];

  float s = 0.f;
  for (int r = rl; r < 256; r += 4) s += X[r*C + c];
  red[rl][cl] = s; __syncthreads();
  if (rl==0) mcol[cl] = (red[0][cl]+red[1][cl]+red[2][cl]+red[3][cl]) * (1.0f/256.0f);
  __syncthreads();
  float m = mcol[cl];
  float s2 = 0.f;
  for (int r = rl; r < 256; r += 4){ float d = X[r*C+c]-m; s2 += d*d; }
  red[rl][cl] = s2; __syncthreads();
  if (rl==0) vcol[cl] = (red[0][cl]+red[1][cl]+red[2][cl]+red[3][cl]) * (1.0f/256.0f);
  __syncthreads();
  float scale = gma[c] * rsqrtf(vcol[cl] + 1e-5f);
  float sh = bta[c];
  for (int r = rl; r < 256; r += 4){
    float v = (X[r*C+c]-m)*scale + sh;
    Y[r*C+c] = v > 0.f ? v : 0.f;
  }
}

// ---------------- row L2-normalize (cols==256); optional transpose output ----------------
__global__ __launch_bounds__(256) void rownorm_kernel(const float* __restrict__ X,
                                                      float* __restrict__ Y,
                                                      float* __restrict__ YT, int nrows){
  const int n = blockIdx.x, t = threadIdx.x;
  const int lane = t & 63, wv = t >> 6;
  float x = X[(size_t)n*256 + t];
  float v = x*x;
  #pragma unroll
  for (int o=32;o;o>>=1) v += __shfl_xor(v,o);
  __shared__ float wsum[4];
  if (lane==0) wsum[wv]=v;
  __syncthreads();
  float total = wsum[0]+wsum[1]+wsum[2]+wsum[3];
  float inv = 1.0f/(sqrtf(total)+1e-6f);
  float y = x*inv;
  Y[(size_t)n*256+t] = y;
  if (YT) YT[(size_t)t*nrows + n] = y;
}

// ---------------- fused softmax + gumbel-argmax + select + outputs ----------------
__global__ __launch_bounds__(256) void sample_kernel(
    const float* __restrict__ S, const float* __restrict__ Hn,
    const float* __restrict__ embed, const float* __restrict__ temp,
    float* __restrict__ probs, float* __restrict__ codef,
    float* __restrict__ quant, float* __restrict__ norms,
    uint32_t kc0, uint32_t kc1, uint32_t kp0, uint32_t kp1){
  const int n = blockIdx.x, t = threadIdx.x;
  const int lane = t & 63, wv = t >> 6;
  __shared__ float wred[4]; __shared__ int wredi[4];
  __shared__ float bsel; __shared__ int bcode;

  const float tv = temp[0];
  const float alpha = 1.0f/(tv*tv);
  const float s = S[(size_t)n*256 + t];
  const float dist = -2.0f*(alpha-1.0f)*s - 2.0f*s;
  const float L = -dist;

  // softmax max
  float m = L;
  #pragma unroll
  for (int o=32;o;o>>=1) m = fmaxf(m, __shfl_xor(m,o));
  if (lane==0) wred[wv]=m;
  __syncthreads();
  m = fmaxf(fmaxf(wred[0],wred[1]), fmaxf(wred[2],wred[3]));
  __syncthreads();

  const float e = expf(L - m);
  float se = e;
  #pragma unroll
  for (int o=32;o;o>>=1) se += __shfl_xor(se,o);
  if (lane==0) wred[wv]=se;
  __syncthreads();
  const float sum = wred[0]+wred[1]+wred[2]+wred[3];
  __syncthreads();
  const float A = e / sum;

  // gumbel noise, exact JAX bit path
  const uint32_t bits = random_bits32(kc0,kc1,(uint32_t)(n*256+t), 4194304u);
  const float f = __uint_as_float((bits>>9) | 0x3f800000u) - 1.0f;
  const float TINY = 1.17549435082228751e-38f;
  const float u = fmaxf(TINY, f + TINY);
  const float g = -logf(-logf(u));
  float z = L + g;
  int idx = t;
  #pragma unroll
  for (int o=32;o;o>>=1){
    float zo = __shfl_xor(z,o); int io = __shfl_xor(idx,o);
    if (zo > z || (zo == z && io < idx)){ z = zo; idx = io; }
  }
  if (lane==0){ wred[wv]=z; wredi[wv]=idx; }
  __syncthreads();
  if (t==0){
    float zb = wred[0]; int ib = wredi[0];
    #pragma unroll
    for (int w=1; w<4; w++)
      if (wred[w] > zb || (wred[w]==zb && wredi[w]<ib)){ zb=wred[w]; ib=wredi[w]; }
    const uint32_t pb = random_bits32(kp0,kp1,(uint32_t)n, 16384u);
    const float pf = __uint_as_float((pb>>9) | 0x3f800000u) - 1.0f;
    bsel = (pf > 0.0f) ? 1.0f : 0.0f;
    bcode = ib;
  }
  __syncthreads();
  const float sel = bsel; const int code = bcode;

  probs[(size_t)n*256 + t] = A * sel;
  const float ev = embed[(size_t)code*256 + t];
  quant[(size_t)n*256 + t] = ev * sel;
  const float h = Hn[(size_t)n*256 + t];
  const float d = ev - h;
  float dq = d*d;
  #pragma unroll
  for (int o=32;o;o>>=1) dq += __shfl_xor(dq,o);
  if (lane==0) wred[wv]=dq;
  __syncthreads();
  if (t==0){
    norms[n] = sqrtf(wred[0]+wred[1]+wred[2]+wred[3]);
    codef[n] = (float)code * sel;
  }
}

// ---------------- vq_loss = mean(norms) ----------------
__global__ __launch_bounds__(256) void loss_kernel(const float* __restrict__ norms,
                                                   float* __restrict__ outp){
  const int t = threadIdx.x;
  float s = 0.f;
  for (int i=t;i<32768;i+=256) s += norms[i];
  #pragma unroll
  for (int o=32;o;o>>=1) s += __shfl_xor(s,o);
  __shared__ float wred[4];
  if ((t&63)==0) wred[t>>6]=s;
  __syncthreads();
  if (t==0) outp[0] = (wred[0]+wred[1]+wred[2]+wred[3]) * (1.0f/32768.0f);
}

// ---------------- launch ----------------
extern "C" void kernel_launch(void* const* d_in, const int* in_sizes, int n_in,
                              void* d_out, int out_size, void* d_ws, size_t ws_size,
                              hipStream_t stream){
  const float* h_in  = (const float*)d_in[0];
  const float* temp  = (const float*)d_in[1];
  const float* proj_w= (const float*)d_in[2];
  const float* proj_b= (const float*)d_in[3];
  const float* pinv_w= (const float*)d_in[4];
  const float* pinv_b= (const float*)d_in[5];
  const float* w0 = (const float*)d_in[6];
  const float* b0 = (const float*)d_in[7];
  const float* g0 = (const float*)d_in[8];
  const float* be0= (const float*)d_in[9];
  const float* wm = (const float*)d_in[10];
  const float* bm = (const float*)d_in[11];
  const float* gm = (const float*)d_in[12];
  const float* bem= (const float*)d_in[13];
  const float* wL = (const float*)d_in[14];
  const float* bL = (const float*)d_in[15];

  float* out = (float*)d_out;
  float* q_inv  = out;                  // [32768,2048]
  float* o_code = out + 67108864;       // [32768]
  float* o_quant= out + 67141632;       // [32768,256]
  float* o_probs= out + 75530240;       // [32768,256]
  float* o_loss = out + 83918848;       // [1]

  // scratch inside q_inv region (dead before final GEMM overwrites it)
  float* H      = out + 0;              // [32768,256]
  float* Ssim   = out + 8388608;        // [32768,256]
  float* X0b    = out + 16777216;       // [256,1024]
  float* X1b    = out + 17039360;       // [256,1024]
  float* embed  = out + 17301504;       // [256,256]
  float* embedT = out + 17367040;       // [256,256]
  float* norms  = out + 17432576;       // [32768]

  // host-side key derivation for jax.random.key(42) -> split(2)
  uint32_t kc0,kc1,kp0,kp1;
#if PARTITIONABLE
  threefry2x32(0u,42u, 0u,0u, kc0,kc1);
  threefry2x32(0u,42u, 0u,1u, kp0,kp1);
#else
  { uint32_t a0,b0w,a1,b1w;
    threefry2x32(0u,42u, 0u,2u, a0,b0w);
    threefry2x32(0u,42u, 1u,3u, a1,b1w);
    kc0=a0; kc1=a1; kp0=b0w; kp1=b1w; }
#endif

  // codebook MLP -> embed, embedT
  cb_fc0_kernel<<<1024,256,0,stream>>>(w0, b0, X0b);
  bn_relu_kernel<<<16,256,0,stream>>>(X0b, g0, be0, X1b, 1024);
  for (int l=0;l<4;l++){
    gemm_f32<32,32,2,2><<<dim3(32,8),256,0,stream>>>(X1b, wm + (size_t)l*1024*1024, bm + l*1024, X0b, 256,1024,1024);
    bn_relu_kernel<<<16,256,0,stream>>>(X0b, gm + l*1024, bem + l*1024, X1b, 1024);
  }
  gemm_f32<32,32,2,2><<<dim3(8,8),256,0,stream>>>(X1b, wL, bL, X0b, 256,256,1024);
  rownorm_kernel<<<256,256,0,stream>>>(X0b, embed, embedT, 256);

  // h path
  gemm_f32<128,128,8,8><<<dim3(2,256),256,0,stream>>>(h_in, proj_w, proj_b, H, 32768,256,2048);
  rownorm_kernel<<<32768,256,0,stream>>>(H, H, nullptr, 32768);
  gemm_f32<128,128,8,8><<<dim3(2,256),256,0,stream>>>(H, embedT, nullptr, Ssim, 32768,256,256);

  // sampling + small outputs
  sample_kernel<<<32768,256,0,stream>>>(Ssim, H, embed, temp, o_probs, o_code, o_quant, norms,
                                        kc0,kc1,kp0,kp1);
  loss_kernel<<<1,256,0,stream>>>(norms, o_loss);

  // final projection (overwrites all scratch in region 0)
  gemm_f32<128,128,8,8><<<dim3(16,256),256,0,stream>>>(o_quant, pinv_w, pinv_b, q_inv, 32768,2048,256);
}

// Round 2
// 899.155 us; speedup vs baseline: 1.7094x; 1.7094x over previous
//
#include <hip/hip_runtime.h>
#include <hip/hip_bf16.h>
#include <stdint.h>
#include <stddef.h>

#ifndef PARTITIONABLE
#define PARTITIONABLE 1
#endif

typedef __attribute__((ext_vector_type(8))) short short8;
typedef __attribute__((ext_vector_type(4))) float f32x4;

// ---------------- threefry2x32 (exact JAX) ----------------
__host__ __device__ __forceinline__ uint32_t rotl32(uint32_t x, int d){ return (x<<d)|(x>>(32-d)); }

__host__ __device__ __forceinline__ void tf4(uint32_t&x0, uint32_t&x1, int r0,int r1,int r2,int r3){
  x0+=x1; x1=rotl32(x1,r0); x1^=x0;
  x0+=x1; x1=rotl32(x1,r1); x1^=x0;
  x0+=x1; x1=rotl32(x1,r2); x1^=x0;
  x0+=x1; x1=rotl32(x1,r3); x1^=x0;
}
__host__ __device__ __forceinline__ void threefry2x32(uint32_t k0,uint32_t k1,uint32_t x0,uint32_t x1,
                                                      uint32_t&y0,uint32_t&y1){
  uint32_t ks2 = k0^k1^0x1BD11BDAu;
  x0+=k0; x1+=k1;
  tf4(x0,x1,13,15,26,6);  x0+=k1;  x1+=ks2+1u;
  tf4(x0,x1,17,29,16,24); x0+=ks2; x1+=k0+2u;
  tf4(x0,x1,13,15,26,6);  x0+=k0;  x1+=k1+3u;
  tf4(x0,x1,17,29,16,24); x0+=k1;  x1+=ks2+4u;
  tf4(x0,x1,13,15,26,6);  x0+=ks2; x1+=k0+5u;
  y0=x0; y1=x1;
}

__device__ __forceinline__ uint32_t random_bits32(uint32_t k0,uint32_t k1,uint32_t idx, uint32_t half){
#if PARTITIONABLE
  uint32_t y0,y1; threefry2x32(k0,k1, 0u, idx, y0,y1);
  (void)half;
  return y0 ^ y1;
#else
  uint32_t y0,y1;
  if (idx < half) { threefry2x32(k0,k1, idx, idx+half, y0,y1); return y0; }
  else            { threefry2x32(k0,k1, idx-half, idx, y0,y1); return y1; }
#endif
}

// ---------------- bf16 split helpers ----------------
__device__ __forceinline__ unsigned short bf16_rne(float x){
  unsigned u = __float_as_uint(x);
  unsigned r = (u + 0x7FFFu + ((u>>16)&1u)) >> 16;
  return (unsigned short)r;
}
__device__ __forceinline__ float bf16_tof(unsigned short h){
  return __uint_as_float(((unsigned)h)<<16);
}

// ---------------- Markidis split-2 bf16 MFMA GEMM ----------------
// C[M][N] = A[M][K] @ B[K][N] (+bias). A row-major (K contig), B row-major (N contig).
// Requires M%128==0, N%128==0, K%32==0.
// 128x128 tile, BK=32, 4 waves of 64x64, mfma_f32_16x16x32_bf16, 3 products (hh, h*lo, lo*h).
__global__ __launch_bounds__(256) void gemm_markidis(
    const float* __restrict__ A, const float* __restrict__ B,
    const float* __restrict__ bias, float* __restrict__ C,
    int M, int N, int K){
  __shared__ unsigned short Ahi[4096], Alo[4096], Bhi[4096], Blo[4096];
  const int tid  = threadIdx.x;
  const int lane = tid & 63;
  const int wv   = tid >> 6;            // 0..3
  const int wr   = wv >> 1, wc = wv & 1;
  const int bm = blockIdx.y * 128, bn = blockIdx.x * 128;

  f32x4 acc[4][4];
  #pragma unroll
  for (int i=0;i<4;i++)
    #pragma unroll
    for (int j=0;j<4;j++) acc[i][j] = (f32x4){0.f,0.f,0.f,0.f};

  const int arow = tid >> 1, ahalf = tid & 1;   // A: 128 rows x 2 k-halves of 16
  const int bcol = tid & 127, bkh = tid >> 7;   // B: 128 cols x 2 k-halves of 16
  const int swA = (arow>>1)&3;
  const int swB = (bcol>>1)&3;

  for (int k0 = 0; k0 < K; k0 += 32){
    // ---- load A: 16 contiguous f32 (row arow, k-window ahalf*16) ----
    const float4* pa = (const float4*)(A + (size_t)(bm + arow)*K + k0 + ahalf*16);
    float4 a0 = pa[0], a1 = pa[1], a2 = pa[2], a3 = pa[3];
    float af[16] = {a0.x,a0.y,a0.z,a0.w, a1.x,a1.y,a1.z,a1.w,
                    a2.x,a2.y,a2.z,a2.w, a3.x,a3.y,a3.z,a3.w};
    // ---- load B: 16 f32 down a column (coalesced across lanes per instr) ----
    float bf[16];
    const float* pb = B + (size_t)(k0 + bkh*16)*N + bn + bcol;
    #pragma unroll
    for (int j=0;j<16;j++) bf[j] = pb[(size_t)j*N];

    // ---- split + write A ----
    {
      short8 vh0, vh1, vl0, vl1;
      #pragma unroll
      for (int e=0;e<8;e++){
        unsigned short h = bf16_rne(af[e]);
        vh0[e] = (short)h;
        vl0[e] = (short)bf16_rne(af[e] - bf16_tof(h));
      }
      #pragma unroll
      for (int e=0;e<8;e++){
        unsigned short h = bf16_rne(af[8+e]);
        vh1[e] = (short)h;
        vl1[e] = (short)bf16_rne(af[8+e] - bf16_tof(h));
      }
      const int s0 = ((ahalf*2+0)^swA)*8, s1 = ((ahalf*2+1)^swA)*8;
      *(short8*)&Ahi[arow*32 + s0] = vh0;
      *(short8*)&Ahi[arow*32 + s1] = vh1;
      *(short8*)&Alo[arow*32 + s0] = vl0;
      *(short8*)&Alo[arow*32 + s1] = vl1;
    }
    // ---- split + write B (transposed layout: [col][k]) ----
    {
      short8 vh0, vh1, vl0, vl1;
      #pragma unroll
      for (int e=0;e<8;e++){
        unsigned short h = bf16_rne(bf[e]);
        vh0[e] = (short)h;
        vl0[e] = (short)bf16_rne(bf[e] - bf16_tof(h));
      }
      #pragma unroll
      for (int e=0;e<8;e++){
        unsigned short h = bf16_rne(bf[8+e]);
        vh1[e] = (short)h;
        vl1[e] = (short)bf16_rne(bf[8+e] - bf16_tof(h));
      }
      const int s0 = ((bkh*2+0)^swB)*8, s1 = ((bkh*2+1)^swB)*8;
      *(short8*)&Bhi[bcol*32 + s0] = vh0;
      *(short8*)&Bhi[bcol*32 + s1] = vh1;
      *(short8*)&Blo[bcol*32 + s0] = vl0;
      *(short8*)&Blo[bcol*32 + s1] = vl1;
    }
    __syncthreads();

    // ---- fragments: lane row=l&15, k-group=l>>4 (16x16x32 layout, m89) ----
    short8 ah[4], al[4], bh[4], bl[4];
    const int kg = lane >> 4;
    #pragma unroll
    for (int i=0;i<4;i++){
      const int r = wr*64 + i*16 + (lane&15);
      const int offA = r*32 + ((kg ^ ((r>>1)&3))*8);
      ah[i] = *(const short8*)&Ahi[offA];
      al[i] = *(const short8*)&Alo[offA];
      const int c = wc*64 + i*16 + (lane&15);
      const int offB = c*32 + ((kg ^ ((c>>1)&3))*8);
      bh[i] = *(const short8*)&Bhi[offB];
      bl[i] = *(const short8*)&Blo[offB];
    }
    #pragma unroll
    for (int i=0;i<4;i++)
      #pragma unroll
      for (int j=0;j<4;j++){
        acc[i][j] = __builtin_amdgcn_mfma_f32_16x16x32_bf16(ah[i], bh[j], acc[i][j], 0,0,0);
        acc[i][j] = __builtin_amdgcn_mfma_f32_16x16x32_bf16(ah[i], bl[j], acc[i][j], 0,0,0);
        acc[i][j] = __builtin_amdgcn_mfma_f32_16x16x32_bf16(al[i], bh[j], acc[i][j], 0,0,0);
      }
    __syncthreads();
  }

  // ---- epilogue: C layout col=lane&15, row=(lane>>4)*4+reg ----
  #pragma unroll
  for (int i=0;i<4;i++){
    const int rbase = bm + wr*64 + i*16 + (lane>>4)*4;
    #pragma unroll
    for (int j=0;j<4;j++){
      const int col = bn + wc*64 + j*16 + (lane&15);
      const float bb = bias ? bias[col] : 0.f;
      #pragma unroll
      for (int reg=0; reg<4; reg++){
        C[(size_t)(rbase+reg)*N + col] = acc[i][j][reg] + bb;
      }
    }
  }
}

// ---------------- f32 vector GEMM (kept for the codebook MLP) ----------------
template<int BM, int BN, int TM, int TN>
__global__ __launch_bounds__(256) void gemm_f32(
    const float* __restrict__ A, const float* __restrict__ B,
    const float* __restrict__ bias, float* __restrict__ C,
    int M, int N, int K){
  constexpr int BK = 16;
  constexpr int PAD = 4;
  __shared__ float As[BK][BM+PAD];
  __shared__ float Bs[BK][BN];
  const int tid = threadIdx.x;
  const int bm = blockIdx.y*BM, bn = blockIdx.x*BN;
  constexpr int NT = BN/TN;
  const int tc = tid % NT, tr = tid / NT;
  float acc[TM][TN];
  #pragma unroll
  for (int i=0;i<TM;i++)
    #pragma unroll
    for(int j=0;j<TN;j++) acc[i][j]=0.f;

  constexpr int AQ = BM*(BK/4);
  constexpr int BQ = BK*(BN/4);

  for (int k0=0;k0<K;k0+=BK){
    #pragma unroll
    for (int q=tid; q<AQ; q+=256){
      int m = q >> 2, kq = q & 3;
      const float4 v = *(const float4*)&A[(size_t)(bm+m)*K + k0 + kq*4];
      As[kq*4+0][m]=v.x; As[kq*4+1][m]=v.y; As[kq*4+2][m]=v.z; As[kq*4+3][m]=v.w;
    }
    #pragma unroll
    for (int q=tid; q<BQ; q+=256){
      int kk = q / (BN/4), nq = q % (BN/4);
      *(float4*)&Bs[kk][nq*4] = *(const float4*)&B[(size_t)(k0+kk)*N + bn + nq*4];
    }
    __syncthreads();
    #pragma unroll
    for (int kk=0;kk<BK;kk++){
      float a[TM], b[TN];
      #pragma unroll
      for (int i=0;i<TM;i++) a[i]=As[kk][tr*TM+i];
      #pragma unroll
      for (int j=0;j<TN;j++) b[j]=Bs[kk][tc*TN+j];
      #pragma unroll
      for (int i=0;i<TM;i++)
        #pragma unroll
        for (int j=0;j<TN;j++)
          acc[i][j] += a[i]*b[j];
    }
    __syncthreads();
  }
  #pragma unroll
  for (int i=0;i<TM;i++){
    const size_t row = (size_t)(bm + tr*TM + i);
    #pragma unroll
    for (int j=0;j<TN;j++){
      const size_t col = (size_t)(bn + tc*TN + j);
      float v = acc[i][j];
      if (bias) v += bias[col];
      C[row*(size_t)N + col] = v;
    }
  }
}

// ---------------- codebook first layer ----------------
__global__ __launch_bounds__(256) void cb_fc0_kernel(const float* __restrict__ w0,
                                                     const float* __restrict__ b0,
                                                     float* __restrict__ X0){
  int g = blockIdx.x*256 + threadIdx.x;
  int i = g >> 10, c = g & 1023;
  float acc = b0[c];
  #pragma unroll
  for (int j=0;j<8;j++) if ((i >> (7-j)) & 1) acc += w0[j*1024 + c];
  X0[g] = acc;
}

// ---------------- BN (batch stats over 256 rows) + ReLU ----------------
__global__ __launch_bounds__(256) void bn_relu_kernel(const float* __restrict__ X,
                                                      const float* __restrict__ gma,
                                                      const float* __restrict__ bta,
                                                      float* __restrict__ Y, int C){
  const int c0 = blockIdx.x*64;
  const int t = threadIdx.x;
  const int cl = t & 63, rl = t >> 6;
  const int c = c0 + cl;
  __shared__ float red[4][64];
  __shared__ float mcol[64], vcol[64];

  float s = 0.f;
  for (int r = rl; r < 256; r += 4) s += X[r*C + c];
  red[rl][cl] = s; __syncthreads();
  if (rl==0) mcol[cl] = (red[0][cl]+red[1][cl]+red[2][cl]+red[3][cl]) * (1.0f/256.0f);
  __syncthreads();
  float m = mcol[cl];
  float s2 = 0.f;
  for (int r = rl; r < 256; r += 4){ float d = X[r*C+c]-m; s2 += d*d; }
  red[rl][cl] = s2; __syncthreads();
  if (rl==0) vcol[cl] = (red[0][cl]+red[1][cl]+red[2][cl]+red[3][cl]) * (1.0f/256.0f);
  __syncthreads();
  float scale = gma[c] * rsqrtf(vcol[cl] + 1e-5f);
  float sh = bta[c];
  for (int r = rl; r < 256; r += 4){
    float v = (X[r*C+c]-m)*scale + sh;
    Y[r*C+c] = v > 0.f ? v : 0.f;
  }
}

// ---------------- row L2-normalize (cols==256) ----------------
__global__ __launch_bounds__(256) void rownorm_kernel(const float* __restrict__ X,
                                                      float* __restrict__ Y,
                                                      float* __restrict__ YT, int nrows){
  const int n = blockIdx.x, t = threadIdx.x;
  const int lane = t & 63, wv = t >> 6;
  float x = X[(size_t)n*256 + t];
  float v = x*x;
  #pragma unroll
  for (int o=32;o;o>>=1) v += __shfl_xor(v,o);
  __shared__ float wsum[4];
  if (lane==0) wsum[wv]=v;
  __syncthreads();
  float total = wsum[0]+wsum[1]+wsum[2]+wsum[3];
  float inv = 1.0f/(sqrtf(total)+1e-6f);
  float y = x*inv;
  Y[(size_t)n*256+t] = y;
  if (YT) YT[(size_t)t*nrows + n] = y;
}

// ---------------- fused softmax + gumbel-argmax + select + outputs ----------------
__global__ __launch_bounds__(256) void sample_kernel(
    const float* __restrict__ S, const float* __restrict__ Hn,
    const float* __restrict__ embed, const float* __restrict__ temp,
    float* __restrict__ probs, float* __restrict__ codef,
    float* __restrict__ quant, float* __restrict__ norms,
    uint32_t kc0, uint32_t kc1, uint32_t kp0, uint32_t kp1){
  const int n = blockIdx.x, t = threadIdx.x;
  const int lane = t & 63, wv = t >> 6;
  __shared__ float wred[4]; __shared__ int wredi[4];
  __shared__ float bsel; __shared__ int bcode;

  const float tv = temp[0];
  const float alpha = 1.0f/(tv*tv);
  const float s = S[(size_t)n*256 + t];
  const float dist = -2.0f*(alpha-1.0f)*s - 2.0f*s;
  const float L = -dist;

  float m = L;
  #pragma unroll
  for (int o=32;o;o>>=1) m = fmaxf(m, __shfl_xor(m,o));
  if (lane==0) wred[wv]=m;
  __syncthreads();
  m = fmaxf(fmaxf(wred[0],wred[1]), fmaxf(wred[2],wred[3]));
  __syncthreads();

  const float e = expf(L - m);
  float se = e;
  #pragma unroll
  for (int o=32;o;o>>=1) se += __shfl_xor(se,o);
  if (lane==0) wred[wv]=se;
  __syncthreads();
  const float sum = wred[0]+wred[1]+wred[2]+wred[3];
  __syncthreads();
  const float A = e / sum;

  const uint32_t bits = random_bits32(kc0,kc1,(uint32_t)(n*256+t), 4194304u);
  const float f = __uint_as_float((bits>>9) | 0x3f800000u) - 1.0f;
  const float TINY = 1.17549435082228751e-38f;
  const float u = fmaxf(TINY, f + TINY);
  const float g = -logf(-logf(u));
  float z = L + g;
  int idx = t;
  #pragma unroll
  for (int o=32;o;o>>=1){
    float zo = __shfl_xor(z,o); int io = __shfl_xor(idx,o);
    if (zo > z || (zo == z && io < idx)){ z = zo; idx = io; }
  }
  if (lane==0){ wred[wv]=z; wredi[wv]=idx; }
  __syncthreads();
  if (t==0){
    float zb = wred[0]; int ib = wredi[0];
    #pragma unroll
    for (int w=1; w<4; w++)
      if (wred[w] > zb || (wred[w]==zb && wredi[w]<ib)){ zb=wred[w]; ib=wredi[w]; }
    const uint32_t pb = random_bits32(kp0,kp1,(uint32_t)n, 16384u);
    const float pf = __uint_as_float((pb>>9) | 0x3f800000u) - 1.0f;
    bsel = (pf > 0.0f) ? 1.0f : 0.0f;
    bcode = ib;
  }
  __syncthreads();
  const float sel = bsel; const int code = bcode;

  probs[(size_t)n*256 + t] = A * sel;
  const float ev = embed[(size_t)code*256 + t];
  quant[(size_t)n*256 + t] = ev * sel;
  const float h = Hn[(size_t)n*256 + t];
  const float d = ev - h;
  float dq = d*d;
  #pragma unroll
  for (int o=32;o;o>>=1) dq += __shfl_xor(dq,o);
  if (lane==0) wred[wv]=dq;
  __syncthreads();
  if (t==0){
    norms[n] = sqrtf(wred[0]+wred[1]+wred[2]+wred[3]);
    codef[n] = (float)code * sel;
  }
}

// ---------------- vq_loss = mean(norms) ----------------
__global__ __launch_bounds__(256) void loss_kernel(const float* __restrict__ norms,
                                                   float* __restrict__ outp){
  const int t = threadIdx.x;
  float s = 0.f;
  for (int i=t;i<32768;i+=256) s += norms[i];
  #pragma unroll
  for (int o=32;o;o>>=1) s += __shfl_xor(s,o);
  __shared__ float wred[4];
  if ((t&63)==0) wred[t>>6]=s;
  __syncthreads();
  if (t==0) outp[0] = (wred[0]+wred[1]+wred[2]+wred[3]) * (1.0f/32768.0f);
}

// ---------------- launch ----------------
extern "C" void kernel_launch(void* const* d_in, const int* in_sizes, int n_in,
                              void* d_out, int out_size, void* d_ws, size_t ws_size,
                              hipStream_t stream){
  const float* h_in  = (const float*)d_in[0];
  const float* temp  = (const float*)d_in[1];
  const float* proj_w= (const float*)d_in[2];
  const float* proj_b= (const float*)d_in[3];
  const float* pinv_w= (const float*)d_in[4];
  const float* pinv_b= (const float*)d_in[5];
  const float* w0 = (const float*)d_in[6];
  const float* b0 = (const float*)d_in[7];
  const float* g0 = (const float*)d_in[8];
  const float* be0= (const float*)d_in[9];
  const float* wm = (const float*)d_in[10];
  const float* bm = (const float*)d_in[11];
  const float* gm = (const float*)d_in[12];
  const float* bem= (const float*)d_in[13];
  const float* wL = (const float*)d_in[14];
  const float* bL = (const float*)d_in[15];

  float* out = (float*)d_out;
  float* q_inv  = out;                  // [32768,2048]
  float* o_code = out + 67108864;       // [32768]
  float* o_quant= out + 67141632;       // [32768,256]
  float* o_probs= out + 75530240;       // [32768,256]
  float* o_loss = out + 83918848;       // [1]

  // scratch inside q_inv region (dead before final GEMM overwrites it)
  float* H      = out + 0;              // [32768,256]
  float* Ssim   = out + 8388608;        // [32768,256]
  float* X0b    = out + 16777216;       // [256,1024]
  float* X1b    = out + 17039360;       // [256,1024]
  float* embed  = out + 17301504;       // [256,256]
  float* embedT = out + 17367040;       // [256,256]
  float* norms  = out + 17432576;       // [32768]

  uint32_t kc0,kc1,kp0,kp1;
#if PARTITIONABLE
  threefry2x32(0u,42u, 0u,0u, kc0,kc1);
  threefry2x32(0u,42u, 0u,1u, kp0,kp1);
#else
  { uint32_t a0,b0w,a1,b1w;
    threefry2x32(0u,42u, 0u,2u, a0,b0w);
    threefry2x32(0u,42u, 1u,3u, a1,b1w);
    kc0=a0; kc1=a1; kp0=b0w; kp1=b1w; }
#endif

  // codebook MLP -> embed, embedT (f32 path: protects argmax precision)
  cb_fc0_kernel<<<1024,256,0,stream>>>(w0, b0, X0b);
  bn_relu_kernel<<<16,256,0,stream>>>(X0b, g0, be0, X1b, 1024);
  for (int l=0;l<4;l++){
    gemm_f32<32,32,2,2><<<dim3(32,8),256,0,stream>>>(X1b, wm + (size_t)l*1024*1024, bm + l*1024, X0b, 256,1024,1024);
    bn_relu_kernel<<<16,256,0,stream>>>(X0b, gm + l*1024, bem + l*1024, X1b, 1024);
  }
  gemm_f32<32,32,2,2><<<dim3(8,8),256,0,stream>>>(X1b, wL, bL, X0b, 256,256,1024);
  rownorm_kernel<<<256,256,0,stream>>>(X0b, embed, embedT, 256);

  // h path (MFMA Markidis split-2)
  gemm_markidis<<<dim3(2,256),256,0,stream>>>(h_in, proj_w, proj_b, H, 32768,256,2048);
  rownorm_kernel<<<32768,256,0,stream>>>(H, H, nullptr, 32768);
  gemm_markidis<<<dim3(2,256),256,0,stream>>>(H, embedT, nullptr, Ssim, 32768,256,256);

  // sampling + small outputs
  sample_kernel<<<32768,256,0,stream>>>(Ssim, H, embed, temp, o_probs, o_code, o_quant, norms,
                                        kc0,kc1,kp0,kp1);
  loss_kernel<<<1,256,0,stream>>>(norms, o_loss);

  // final projection (overwrites all scratch in region 0)
  gemm_markidis<<<dim3(16,256),256,0,stream>>>(o_quant, pinv_w, pinv_b, q_inv, 32768,2048,256);
}